// Round 3
// baseline (910.519 us; speedup 1.0000x reference)
//
#include <hip/hip_runtime.h>

typedef unsigned short u16;
typedef __attribute__((ext_vector_type(8))) short short8;
typedef __attribute__((ext_vector_type(4))) float floatx4;

#define R_PDS 0.18033688f   // r_softplus_0 / sqrt(64)

__device__ __forceinline__ float bf2f(u16 u) {
    union { float f; unsigned int i; } c; c.i = ((unsigned int)u) << 16; return c.f;
}
__device__ __forceinline__ u16 f2b(float f) {
    union { float f; unsigned int i; } c; c.f = f;
    unsigned int r = c.i + 0x7fffu + ((c.i >> 16) & 1u);
    return (u16)(r >> 16);
}

// ---------------- flag: is mask nonzero? ----------------
__global__ void zero_flag_k(int* f) { *f = 0; }

__global__ __launch_bounds__(256) void mask_any_k(const float* __restrict__ mask, int* flag) {
    int i = blockIdx.x * 256 + threadIdx.x;   // 4M floats / 4 per thread
    uint4 u = ((const uint4*)mask)[i];
    unsigned int v = (u.x | u.y | u.z | u.w) & 0x7fffffffu;  // ignore -0.0
    if (v) atomicOr(flag, 1);
}

// ---------------- RMSNorm (row = 1024 fp32) -> bf16 ----------------
__global__ __launch_bounds__(256) void rmsnorm_k(const float* __restrict__ in,
                                                 const float* __restrict__ gscale,
                                                 u16* __restrict__ out) {
    int row = blockIdx.x;
    int t = threadIdx.x, lane = t & 63, wave = t >> 6;
    const float* x = in + (size_t)row * 1024;
    float4 v = *(const float4*)(x + t * 4);
    float ss = v.x*v.x + v.y*v.y + v.z*v.z + v.w*v.w;
    for (int o = 1; o < 64; o <<= 1) ss += __shfl_xor(ss, o, 64);
    __shared__ float red[4];
    if (lane == 0) red[wave] = ss;
    __syncthreads();
    float tot = red[0] + red[1] + red[2] + red[3];
    float inv = rsqrtf(tot * (1.0f / 1024.0f) + 1e-6f);
    float4 s = *(const float4*)(gscale + t * 4);
    u16 o0 = f2b(v.x * inv * s.x);
    u16 o1 = f2b(v.y * inv * s.y);
    u16 o2 = f2b(v.z * inv * s.z);
    u16 o3 = f2b(v.w * inv * s.w);
    uint2 w; w.x = (unsigned)o0 | ((unsigned)o1 << 16); w.y = (unsigned)o2 | ((unsigned)o3 << 16);
    *(uint2*)(out + (size_t)row * 1024 + t * 4) = w;
}

// ---------------- LayerNorm (row = 1024 fp32, eff scale = 1+s) -> bf16 ----------------
__global__ __launch_bounds__(256) void layernorm_k(const float* __restrict__ in,
                                                   const float* __restrict__ gs,
                                                   const float* __restrict__ gb,
                                                   u16* __restrict__ out) {
    int row = blockIdx.x;
    int t = threadIdx.x, lane = t & 63, wave = t >> 6;
    const float* x = in + (size_t)row * 1024;
    float4 v = *(const float4*)(x + t * 4);
    float s1 = v.x + v.y + v.z + v.w;
    float s2 = v.x*v.x + v.y*v.y + v.z*v.z + v.w*v.w;
    for (int o = 1; o < 64; o <<= 1) { s1 += __shfl_xor(s1, o, 64); s2 += __shfl_xor(s2, o, 64); }
    __shared__ float r1[4], r2[4];
    if (lane == 0) { r1[wave] = s1; r2[wave] = s2; }
    __syncthreads();
    float mean = (r1[0] + r1[1] + r1[2] + r1[3]) * (1.0f / 1024.0f);
    float var  = (r2[0] + r2[1] + r2[2] + r2[3]) * (1.0f / 1024.0f) - mean * mean;
    var = fmaxf(var, 0.0f);
    float inv = rsqrtf(var + 1e-6f);
    float4 sc = *(const float4*)(gs + t * 4);
    float4 bb = *(const float4*)(gb + t * 4);
    u16 o0 = f2b((v.x - mean) * inv * (1.0f + sc.x) + bb.x);
    u16 o1 = f2b((v.y - mean) * inv * (1.0f + sc.y) + bb.y);
    u16 o2 = f2b((v.z - mean) * inv * (1.0f + sc.z) + bb.z);
    u16 o3 = f2b((v.w - mean) * inv * (1.0f + sc.w) + bb.w);
    uint2 w; w.x = (unsigned)o0 | ((unsigned)o1 << 16); w.y = (unsigned)o2 | ((unsigned)o3 << 16);
    *(uint2*)(out + (size_t)row * 1024 + t * 4) = w;
}

// ---------------- GEMM: C[M,N] = A_bf16[M,K] * B_f32[N,K]^T + bias (+epilogue) ----------
// EPI: 0 = bias, 1 = bias+relu (bf16 out), 2 = bias+residual. OUTF32: C is float*.
// 128x128 tile, BK=32, 4 waves 2x2, 16x16x32 bf16 MFMA. B converted fp32->bf16 in staging.
template <int EPI, bool OUTF32>
__global__ __launch_bounds__(256) void gemm_bt_k(const u16* __restrict__ A,
                                                 const float* __restrict__ B,
                                                 const float* __restrict__ bias,
                                                 const float* __restrict__ res,
                                                 void* __restrict__ Cv,
                                                 int M, int N, int K) {
    __shared__ __align__(16) u16 As[4096];   // 128 rows x 32 k
    __shared__ __align__(16) u16 Bs[4096];
    const int t = threadIdx.x, wave = t >> 6, lane = t & 63;
    const int quad = lane >> 4, ln = lane & 15;
    const int m0 = blockIdx.y * 128, n0 = blockIdx.x * 128;
    const int wm = (wave >> 1) * 64, wn = (wave & 1) * 64;

    floatx4 acc[4][4];
    for (int mt = 0; mt < 4; mt++) for (int nt = 0; nt < 4; nt++) acc[mt][nt] = (floatx4)0.0f;

    const int c0 = t, c1 = t + 256;          // chunk = 8 k-elems of one row; 512 per tile
    const u16*   Ap0 = A + (size_t)(m0 + (c0 >> 2)) * K + (c0 & 3) * 8;
    const u16*   Ap1 = A + (size_t)(m0 + (c1 >> 2)) * K + (c1 & 3) * 8;
    const float* Bp0 = B + (size_t)(n0 + (c0 >> 2)) * K + (c0 & 3) * 8;
    const float* Bp1 = B + (size_t)(n0 + (c1 >> 2)) * K + (c1 & 3) * 8;

    for (int kt = 0; kt < K; kt += 32) {
        uint4 a0 = *(const uint4*)(Ap0 + kt);
        uint4 a1 = *(const uint4*)(Ap1 + kt);
        float4 b00 = *(const float4*)(Bp0 + kt);
        float4 b01 = *(const float4*)(Bp0 + kt + 4);
        float4 b10 = *(const float4*)(Bp1 + kt);
        float4 b11 = *(const float4*)(Bp1 + kt + 4);
        __syncthreads();                      // prior iter's frag reads done
        *(uint4*)&As[c0 * 8] = a0;
        *(uint4*)&As[c1 * 8] = a1;
        uint4 pb;
        pb.x = (unsigned)f2b(b00.x) | ((unsigned)f2b(b00.y) << 16);
        pb.y = (unsigned)f2b(b00.z) | ((unsigned)f2b(b00.w) << 16);
        pb.z = (unsigned)f2b(b01.x) | ((unsigned)f2b(b01.y) << 16);
        pb.w = (unsigned)f2b(b01.z) | ((unsigned)f2b(b01.w) << 16);
        *(uint4*)&Bs[c0 * 8] = pb;
        pb.x = (unsigned)f2b(b10.x) | ((unsigned)f2b(b10.y) << 16);
        pb.y = (unsigned)f2b(b10.z) | ((unsigned)f2b(b10.w) << 16);
        pb.z = (unsigned)f2b(b11.x) | ((unsigned)f2b(b11.y) << 16);
        pb.w = (unsigned)f2b(b11.z) | ((unsigned)f2b(b11.w) << 16);
        *(uint4*)&Bs[c1 * 8] = pb;
        __syncthreads();
        short8 af[4], bfr[4];
        for (int mt = 0; mt < 4; mt++)
            af[mt] = *(const short8*)&As[(wm + mt * 16 + ln) * 32 + quad * 8];
        for (int nt = 0; nt < 4; nt++)
            bfr[nt] = *(const short8*)&Bs[(wn + nt * 16 + ln) * 32 + quad * 8];
        for (int mt = 0; mt < 4; mt++)
            for (int nt = 0; nt < 4; nt++)
                acc[mt][nt] = __builtin_amdgcn_mfma_f32_16x16x32_bf16(af[mt], bfr[nt], acc[mt][nt], 0, 0, 0);
    }

    // C/D layout: col = lane&15, row = quad*4 + reg  [verified m89/m91]
    for (int nt = 0; nt < 4; nt++) {
        int col = n0 + wn + nt * 16 + ln;
        float bv = bias[col];
        for (int mt = 0; mt < 4; mt++) {
            for (int r = 0; r < 4; r++) {
                int row = m0 + wm + mt * 16 + quad * 4 + r;
                float v = acc[mt][nt][r] + bv;
                if (EPI == 1) v = fmaxf(v, 0.0f);
                if (EPI == 2) v += res[(size_t)row * N + col];
                if (OUTF32) ((float*)Cv)[(size_t)row * N + col] = v;
                else        ((u16*)Cv)[(size_t)row * N + col] = f2b(v);
            }
        }
    }
}

// ---------------- flash attention: 1 block = (bh, 128 q rows), BKV=64 ----------------
__global__ __launch_bounds__(256) void attn_k(const u16* __restrict__ q,
                                              const u16* __restrict__ kk,
                                              const u16* __restrict__ v,
                                              const float* __restrict__ mask,
                                              const float* __restrict__ pds,
                                              const int* __restrict__ flag,
                                              u16* __restrict__ o) {
    __shared__ float scale_s[64];
    __shared__ __align__(16) u16 Qs[128][72];
    __shared__ __align__(16) u16 Ks[64][72];
    __shared__ __align__(16) u16 Vs[64][72];    // Vs[d][kv]
    __shared__ __align__(16) u16 Ps[128][72];

    const int t = threadIdx.x, wave = t >> 6, lane = t & 63;
    const int quad = lane >> 4, ln = lane & 15;
    const int qt = blockIdx.x, bh = blockIdx.y;
    const int b = bh >> 4, h = bh & 15;
    const int q0 = qt * 128;

    if (t < 64) {
        float x = pds[t];
        float sp = (x > 20.0f) ? x : log1pf(__expf(x));
        scale_s[t] = R_PDS * sp;
    }
    __syncthreads();

    // stage Q tile, fused per-dim scale
    const u16* qb = q + (((size_t)(b * 2048 + q0)) * 16 + h) * 64;
    for (int c = t; c < 1024; c += 256) {
        int row = c >> 3, seg = c & 7;
        uint4 u = *(const uint4*)(qb + (size_t)row * 1024 + seg * 8);
        unsigned int uw[4] = {u.x, u.y, u.z, u.w};
        __align__(16) u16 tmp[8];
        for (int e = 0; e < 4; e++) {
            float lo = bf2f((u16)(uw[e] & 0xffff)) * scale_s[seg * 8 + e * 2];
            float hi = bf2f((u16)(uw[e] >> 16))    * scale_s[seg * 8 + e * 2 + 1];
            tmp[e * 2] = f2b(lo); tmp[e * 2 + 1] = f2b(hi);
        }
        *(uint4*)&Qs[row][seg * 8] = *(const uint4*)tmp;
    }

    floatx4 acc_o[2][4];
    float m_i[2][4], l_i[2][4];
    for (int mt = 0; mt < 2; mt++)
        for (int r = 0; r < 4; r++) { m_i[mt][r] = -1e30f; l_i[mt][r] = 0.0f; }
    for (int mt = 0; mt < 2; mt++)
        for (int dt = 0; dt < 4; dt++) acc_o[mt][dt] = (floatx4)0.0f;

    const int mflag = *flag;
    const u16* kb = kk + (((size_t)(b * 2048)) * 16 + h) * 64;
    const u16* vg = v  + (((size_t)(b * 2048)) * 16 + h) * 64;

    for (int kv0 = 0; kv0 < 2048; kv0 += 64) {
        __syncthreads();
        for (int c = t; c < 512; c += 256) {
            int row = c >> 3, seg = c & 7;
            *(uint4*)&Ks[row][seg * 8] = *(const uint4*)(kb + (size_t)(kv0 + row) * 1024 + seg * 8);
            uint4 u = *(const uint4*)(vg + (size_t)(kv0 + row) * 1024 + seg * 8);
            unsigned int uw[4] = {u.x, u.y, u.z, u.w};
            for (int e = 0; e < 4; e++) {
                Vs[seg * 8 + e * 2][row]     = (u16)(uw[e] & 0xffff);
                Vs[seg * 8 + e * 2 + 1][row] = (u16)(uw[e] >> 16);
            }
        }
        __syncthreads();

        // S = Q K^T  (wave: 32 q rows x 64 kv cols)
        floatx4 acc_s[2][4];
        for (int mt = 0; mt < 2; mt++) for (int nt = 0; nt < 4; nt++) acc_s[mt][nt] = (floatx4)0.0f;
        for (int ks = 0; ks < 2; ks++) {
            short8 a0 = *(const short8*)&Qs[wave * 32 + ln][ks * 32 + quad * 8];
            short8 a1 = *(const short8*)&Qs[wave * 32 + 16 + ln][ks * 32 + quad * 8];
            for (int nt = 0; nt < 4; nt++) {
                short8 bfr = *(const short8*)&Ks[nt * 16 + ln][ks * 32 + quad * 8];
                acc_s[0][nt] = __builtin_amdgcn_mfma_f32_16x16x32_bf16(a0, bfr, acc_s[0][nt], 0, 0, 0);
                acc_s[1][nt] = __builtin_amdgcn_mfma_f32_16x16x32_bf16(a1, bfr, acc_s[1][nt], 0, 0, 0);
            }
        }
        if (mflag) {
            for (int mt = 0; mt < 2; mt++)
                for (int nt = 0; nt < 4; nt++)
                    for (int r = 0; r < 4; r++) {
                        int qr = q0 + wave * 32 + mt * 16 + quad * 4 + r;
                        int kc = kv0 + nt * 16 + ln;
                        acc_s[mt][nt][r] += mask[(size_t)qr * 2048 + kc];
                    }
        }

        // online softmax (reduce over ln within quad)
        for (int mt = 0; mt < 2; mt++) {
            for (int r = 0; r < 4; r++) {
                float mx = fmaxf(fmaxf(acc_s[mt][0][r], acc_s[mt][1][r]),
                                 fmaxf(acc_s[mt][2][r], acc_s[mt][3][r]));
                for (int ofs = 1; ofs < 16; ofs <<= 1) mx = fmaxf(mx, __shfl_xor(mx, ofs, 64));
                float mnew = fmaxf(m_i[mt][r], mx);
                float p0 = __expf(acc_s[mt][0][r] - mnew);
                float p1 = __expf(acc_s[mt][1][r] - mnew);
                float p2 = __expf(acc_s[mt][2][r] - mnew);
                float p3 = __expf(acc_s[mt][3][r] - mnew);
                float rs = p0 + p1 + p2 + p3;
                for (int ofs = 1; ofs < 16; ofs <<= 1) rs += __shfl_xor(rs, ofs, 64);
                float alpha = __expf(m_i[mt][r] - mnew);
                l_i[mt][r] = l_i[mt][r] * alpha + rs;
                m_i[mt][r] = mnew;
                for (int dt = 0; dt < 4; dt++)
                    acc_o[mt][dt][r] = acc_o[mt][dt][r] * alpha;
                int prow = wave * 32 + mt * 16 + quad * 4 + r;
                Ps[prow][ln]      = f2b(p0);
                Ps[prow][16 + ln] = f2b(p1);
                Ps[prow][32 + ln] = f2b(p2);
                Ps[prow][48 + ln] = f2b(p3);
            }
        }
        __syncthreads();

        // O += P V
        for (int ks = 0; ks < 2; ks++) {
            short8 a0 = *(const short8*)&Ps[wave * 32 + ln][ks * 32 + quad * 8];
            short8 a1 = *(const short8*)&Ps[wave * 32 + 16 + ln][ks * 32 + quad * 8];
            for (int dt = 0; dt < 4; dt++) {
                short8 bfr = *(const short8*)&Vs[dt * 16 + ln][ks * 32 + quad * 8];
                acc_o[0][dt] = __builtin_amdgcn_mfma_f32_16x16x32_bf16(a0, bfr, acc_o[0][dt], 0, 0, 0);
                acc_o[1][dt] = __builtin_amdgcn_mfma_f32_16x16x32_bf16(a1, bfr, acc_o[1][dt], 0, 0, 0);
            }
        }
    }

    // write O -> o[b, s, h, d] bf16
    u16* ob = o + (((size_t)(b * 2048 + q0)) * 16 + h) * 64;
    for (int mt = 0; mt < 2; mt++) {
        for (int r = 0; r < 4; r++) {
            float inv = 1.0f / l_i[mt][r];
            int row = wave * 32 + mt * 16 + quad * 4 + r;
            for (int dt = 0; dt < 4; dt++)
                ob[(size_t)row * 1024 + dt * 16 + ln] = f2b(acc_o[mt][dt][r] * inv);
        }
    }
}

extern "C" void kernel_launch(void* const* d_in, const int* in_sizes, int n_in,
                              void* d_out, int out_size, void* d_ws, size_t ws_size,
                              hipStream_t stream) {
    const float* inp    = (const float*)d_in[0];
    const float* mask   = (const float*)d_in[1];
    const float* rms_s  = (const float*)d_in[2];
    const float* Wq     = (const float*)d_in[3];
    const float* bq     = (const float*)d_in[4];
    const float* Wk     = (const float*)d_in[5];
    const float* bk     = (const float*)d_in[6];
    const float* Wv     = (const float*)d_in[7];
    const float* bv     = (const float*)d_in[8];
    const float* pds    = (const float*)d_in[9];
    const float* Wpost  = (const float*)d_in[10];
    const float* bpost  = (const float*)d_in[11];
    const float* ln_s   = (const float*)d_in[12];
    const float* ln_b   = (const float*)d_in[13];
    const float* W1     = (const float*)d_in[14];
    const float* b1     = (const float*)d_in[15];
    const float* W2     = (const float*)d_in[16];
    const float* b2     = (const float*)d_in[17];
    float* out = (float*)d_out;

    char* w = (char*)d_ws;
    const size_t MB16 = 1u << 24;
    u16*   x    = (u16*)(w + 0 * MB16);        // [0,16MB) rmsnorm out bf16; later o
    u16*   qb   = (u16*)(w + 1 * MB16);        // [16,32) q bf16
    u16*   kb   = (u16*)(w + 2 * MB16);        // [32,48) k bf16
    u16*   vb   = (u16*)(w + 3 * MB16);        // [48,64) v bf16
    u16*   o    = x;                            // [0,16) after QKV dead
    float* h    = (float*)(w + 1 * MB16);      // [16,48) fp32, over q+k (dead)
    u16*   yln  = x;                            // [0,16) over o (dead after post gemm)
    u16*   f1   = vb;                           // [48,112) over v (dead) + fresh
    int*   flag = (int*)(w + 7 * MB16);        // at 112MB

    zero_flag_k<<<1, 1, 0, stream>>>(flag);
    mask_any_k<<<4096, 256, 0, stream>>>(mask, flag);

    rmsnorm_k<<<8192, 256, 0, stream>>>(inp, rms_s, x);

    gemm_bt_k<0, false><<<dim3(8, 64), 256, 0, stream>>>(x, Wq, bq, nullptr, qb, 8192, 1024, 1024);
    gemm_bt_k<0, false><<<dim3(8, 64), 256, 0, stream>>>(x, Wk, bk, nullptr, kb, 8192, 1024, 1024);
    gemm_bt_k<0, false><<<dim3(8, 64), 256, 0, stream>>>(x, Wv, bv, nullptr, vb, 8192, 1024, 1024);

    attn_k<<<dim3(16, 64), 256, 0, stream>>>(qb, kb, vb, mask, pds, flag, o);

    gemm_bt_k<2, true><<<dim3(8, 64), 256, 0, stream>>>(o, Wpost, bpost, inp, h, 8192, 1024, 1024);

    layernorm_k<<<8192, 256, 0, stream>>>(h, ln_s, ln_b, yln);

    gemm_bt_k<1, false><<<dim3(32, 64), 256, 0, stream>>>(yln, W1, b1, nullptr, f1, 8192, 4096, 1024);
    gemm_bt_k<2, true><<<dim3(8, 64), 256, 0, stream>>>(f1, W2, b2, h, out, 8192, 1024, 4096);
}

// Round 4
// 671.588 us; speedup vs baseline: 1.3558x; 1.3558x over previous
//
#include <hip/hip_runtime.h>

typedef unsigned short u16;
typedef __attribute__((ext_vector_type(8))) short short8;
typedef __attribute__((ext_vector_type(4))) float floatx4;

#define R_PDS 0.18033688f   // r_softplus_0 / sqrt(64)

__device__ __forceinline__ float bf2f(u16 u) {
    union { float f; unsigned int i; } c; c.i = ((unsigned int)u) << 16; return c.f;
}
__device__ __forceinline__ u16 f2b(float f) {
    union { float f; unsigned int i; } c; c.f = f;
    unsigned int r = c.i + 0x7fffu + ((c.i >> 16) & 1u);
    return (u16)(r >> 16);
}

// async global->LDS, 16B per lane. LDS dest is wave-uniform base + lane*16.
__device__ __forceinline__ void async16(const u16* g, u16* l) {
    __builtin_amdgcn_global_load_lds(
        (const __attribute__((address_space(1))) unsigned int*)g,
        (__attribute__((address_space(3))) unsigned int*)l, 16, 0, 0);
}

// ---------------- fp32 -> bf16 convert (weights), 4 elems/thread ----------------
__global__ __launch_bounds__(256) void f2b_k(const float* __restrict__ in, u16* __restrict__ out) {
    int i = blockIdx.x * 256 + threadIdx.x;
    float4 v = ((const float4*)in)[i];
    uint2 w;
    w.x = (unsigned)f2b(v.x) | ((unsigned)f2b(v.y) << 16);
    w.y = (unsigned)f2b(v.z) | ((unsigned)f2b(v.w) << 16);
    ((uint2*)out)[i] = w;
}

// ---------------- flag: is mask nonzero? ----------------
__global__ void zero_flag_k(int* f) { *f = 0; }

__global__ __launch_bounds__(256) void mask_any_k(const float* __restrict__ mask, int* flag) {
    int i = blockIdx.x * 256 + threadIdx.x;
    uint4 u = ((const uint4*)mask)[i];
    unsigned int v = (u.x | u.y | u.z | u.w) & 0x7fffffffu;
    if (v) atomicOr(flag, 1);
}

// ---------------- RMSNorm (row = 1024 fp32) -> bf16 ----------------
__global__ __launch_bounds__(256) void rmsnorm_k(const float* __restrict__ in,
                                                 const float* __restrict__ gscale,
                                                 u16* __restrict__ out) {
    int row = blockIdx.x;
    int t = threadIdx.x, lane = t & 63, wave = t >> 6;
    const float* x = in + (size_t)row * 1024;
    float4 v = *(const float4*)(x + t * 4);
    float ss = v.x*v.x + v.y*v.y + v.z*v.z + v.w*v.w;
    for (int o = 1; o < 64; o <<= 1) ss += __shfl_xor(ss, o, 64);
    __shared__ float red[4];
    if (lane == 0) red[wave] = ss;
    __syncthreads();
    float tot = red[0] + red[1] + red[2] + red[3];
    float inv = rsqrtf(tot * (1.0f / 1024.0f) + 1e-6f);
    float4 s = *(const float4*)(gscale + t * 4);
    uint2 w;
    w.x = (unsigned)f2b(v.x * inv * s.x) | ((unsigned)f2b(v.y * inv * s.y) << 16);
    w.y = (unsigned)f2b(v.z * inv * s.z) | ((unsigned)f2b(v.w * inv * s.w) << 16);
    *(uint2*)(out + (size_t)row * 1024 + t * 4) = w;
}

// ---------------- LayerNorm (row = 1024 bf16 in, eff scale = 1+s) -> bf16 ----------------
__global__ __launch_bounds__(256) void layernorm_k(const u16* __restrict__ in,
                                                   const float* __restrict__ gs,
                                                   const float* __restrict__ gb,
                                                   u16* __restrict__ out) {
    int row = blockIdx.x;
    int t = threadIdx.x, lane = t & 63, wave = t >> 6;
    const u16* x = in + (size_t)row * 1024;
    uint2 u = *(const uint2*)(x + t * 4);
    float v0 = bf2f((u16)(u.x & 0xffff)), v1 = bf2f((u16)(u.x >> 16));
    float v2 = bf2f((u16)(u.y & 0xffff)), v3 = bf2f((u16)(u.y >> 16));
    float s1 = v0 + v1 + v2 + v3;
    float s2 = v0*v0 + v1*v1 + v2*v2 + v3*v3;
    for (int o = 1; o < 64; o <<= 1) { s1 += __shfl_xor(s1, o, 64); s2 += __shfl_xor(s2, o, 64); }
    __shared__ float r1[4], r2[4];
    if (lane == 0) { r1[wave] = s1; r2[wave] = s2; }
    __syncthreads();
    float mean = (r1[0] + r1[1] + r1[2] + r1[3]) * (1.0f / 1024.0f);
    float var  = (r2[0] + r2[1] + r2[2] + r2[3]) * (1.0f / 1024.0f) - mean * mean;
    var = fmaxf(var, 0.0f);
    float inv = rsqrtf(var + 1e-6f);
    float4 sc = *(const float4*)(gs + t * 4);
    float4 bb = *(const float4*)(gb + t * 4);
    uint2 w;
    w.x = (unsigned)f2b((v0 - mean) * inv * (1.0f + sc.x) + bb.x)
        | ((unsigned)f2b((v1 - mean) * inv * (1.0f + sc.y) + bb.y) << 16);
    w.y = (unsigned)f2b((v2 - mean) * inv * (1.0f + sc.z) + bb.z)
        | ((unsigned)f2b((v3 - mean) * inv * (1.0f + sc.w) + bb.w) << 16);
    *(uint2*)(out + (size_t)row * 1024 + t * 4) = w;
}

// ---------------- GEMM: C[M,N] = A_bf16[M,K] * B_bf16[N,K]^T + bias (+epilogue) --------
// EPI: 0 bias, 1 bias+relu, 2 bias+residual. OUTF32: C fp32 else bf16. RESF32: res dtype.
// m97 structure: 128x128 tile, BK=32, 4 waves 2x2, 16x16x32 MFMA, global_load_lds x16B.
template <int EPI, bool OUTF32, bool RESF32>
__global__ __launch_bounds__(256) void gemm_bt_k(const u16* __restrict__ A,
                                                 const u16* __restrict__ B,
                                                 const float* __restrict__ bias,
                                                 const void* __restrict__ res,
                                                 void* __restrict__ Cv,
                                                 int M, int N, int K) {
    __shared__ __align__(16) u16 As[4096];   // 128 rows x 32 k (DMA layout, unpadded)
    __shared__ __align__(16) u16 Bs[4096];
    const int t = threadIdx.x, wave = t >> 6, lane = t & 63;
    const int quad = lane >> 4, ln = lane & 15;
    const int m0 = blockIdx.y * 128, n0 = blockIdx.x * 128;
    const int wm = (wave >> 1) * 64, wn = (wave & 1) * 64;

    floatx4 acc[4][4];
    for (int mt = 0; mt < 4; mt++) for (int nt = 0; nt < 4; nt++) acc[mt][nt] = (floatx4)0.0f;

    const int c0 = t, c1 = t + 256;          // 16B chunks (512 per tile)
    const u16* Ap0 = A + (size_t)(m0 + (c0 >> 2)) * K + (c0 & 3) * 8;
    const u16* Ap1 = A + (size_t)(m0 + (c1 >> 2)) * K + (c1 & 3) * 8;
    const u16* Bp0 = B + (size_t)(n0 + (c0 >> 2)) * K + (c0 & 3) * 8;
    const u16* Bp1 = B + (size_t)(n0 + (c1 >> 2)) * K + (c1 & 3) * 8;
    u16* AsW0 = As + wave * 512;             // wave-uniform LDS bases
    u16* AsW1 = As + 2048 + wave * 512;
    u16* BsW0 = Bs + wave * 512;
    u16* BsW1 = Bs + 2048 + wave * 512;

    for (int kt = 0; kt < K; kt += 32) {
        __syncthreads();
        async16(Ap0 + kt, AsW0);
        async16(Ap1 + kt, AsW1);
        async16(Bp0 + kt, BsW0);
        async16(Bp1 + kt, BsW1);
        __syncthreads();
        short8 af[4], bfr[4];
        for (int mt = 0; mt < 4; mt++)
            af[mt] = *(const short8*)&As[(wm + mt * 16 + ln) * 32 + quad * 8];
        for (int nt = 0; nt < 4; nt++)
            bfr[nt] = *(const short8*)&Bs[(wn + nt * 16 + ln) * 32 + quad * 8];
        for (int mt = 0; mt < 4; mt++)
            for (int nt = 0; nt < 4; nt++)
                acc[mt][nt] = __builtin_amdgcn_mfma_f32_16x16x32_bf16(af[mt], bfr[nt], acc[mt][nt], 0, 0, 0);
    }

    // C/D layout: col = lane&15, row = quad*4 + reg  [verified m89/m91]
    for (int nt = 0; nt < 4; nt++) {
        int col = n0 + wn + nt * 16 + ln;
        float bv = bias[col];
        for (int mt = 0; mt < 4; mt++) {
            for (int r = 0; r < 4; r++) {
                int row = m0 + wm + mt * 16 + quad * 4 + r;
                float v = acc[mt][nt][r] + bv;
                if (EPI == 1) v = fmaxf(v, 0.0f);
                if (EPI == 2) {
                    if (RESF32) v += ((const float*)res)[(size_t)row * N + col];
                    else        v += bf2f(((const u16*)res)[(size_t)row * N + col]);
                }
                if (OUTF32) ((float*)Cv)[(size_t)row * N + col] = v;
                else        ((u16*)Cv)[(size_t)row * N + col] = f2b(v);
            }
        }
    }
}

// ---------------- V transpose: v[b,s,h,d] -> vT[bh][d][s] ----------------
__global__ __launch_bounds__(256) void transpose_v_k(const u16* __restrict__ v, u16* __restrict__ vT) {
    __shared__ u16 tile[64][65];
    int st = blockIdx.x, bh = blockIdx.y;
    int b = bh >> 4, h = bh & 15;
    const u16* vb = v + (((size_t)(b * 2048 + st * 64)) * 16 + h) * 64;
    int t = threadIdx.x;
    for (int i = t; i < 4096; i += 256) {
        int s = i >> 6, d = i & 63;
        tile[s][d] = vb[(size_t)s * 1024 + d];
    }
    __syncthreads();
    u16* ob = vT + (size_t)bh * 131072 + st * 64;
    for (int i = t; i < 4096; i += 256) {
        int d = i >> 6, s = i & 63;
        ob[(size_t)d * 2048 + s] = tile[s][d];
    }
}

// ---------------- flash attention: 1 block = (bh, 128 q rows), BKV=64 ----------------
// No online max (S clamped at 60 before exp); row-sum l via all-ones B-fragment MFMA.
__global__ __launch_bounds__(256) void attn_k(const u16* __restrict__ q,
                                              const u16* __restrict__ kk,
                                              const u16* __restrict__ vT,
                                              const float* __restrict__ mask,
                                              const float* __restrict__ pds,
                                              const int* __restrict__ flag,
                                              u16* __restrict__ o) {
    __shared__ float scale_s[64];
    __shared__ __align__(16) u16 Qs[128][72];
    __shared__ __align__(16) u16 Ks[64][72];
    __shared__ __align__(16) u16 Vs[64][72];    // rows = d, cols = kv (from vT, no scatter)
    __shared__ __align__(16) u16 Ps[128][72];

    const int t = threadIdx.x, wave = t >> 6, lane = t & 63;
    const int quad = lane >> 4, ln = lane & 15;
    const int qt = blockIdx.x, bh = blockIdx.y;
    const int b = bh >> 4, h = bh & 15;
    const int q0 = qt * 128;

    if (t < 64) {
        float x = pds[t];
        float sp = (x > 20.0f) ? x : log1pf(__expf(x));
        scale_s[t] = R_PDS * sp;
    }
    __syncthreads();

    // stage Q tile, fused per-dim scale
    const u16* qb = q + (((size_t)(b * 2048 + q0)) * 16 + h) * 64;
    for (int c = t; c < 1024; c += 256) {
        int row = c >> 3, seg = c & 7;
        uint4 u = *(const uint4*)(qb + (size_t)row * 1024 + seg * 8);
        unsigned int uw[4] = {u.x, u.y, u.z, u.w};
        __align__(16) u16 tmp[8];
        for (int e = 0; e < 4; e++) {
            float lo = bf2f((u16)(uw[e] & 0xffff)) * scale_s[seg * 8 + e * 2];
            float hi = bf2f((u16)(uw[e] >> 16))    * scale_s[seg * 8 + e * 2 + 1];
            tmp[e * 2] = f2b(lo); tmp[e * 2 + 1] = f2b(hi);
        }
        *(uint4*)&Qs[row][seg * 8] = *(const uint4*)tmp;
    }
    __syncthreads();

    // hoist Q fragments (loop-invariant)
    short8 qf[2][2];
    for (int mt = 0; mt < 2; mt++)
        for (int ks = 0; ks < 2; ks++)
            qf[mt][ks] = *(const short8*)&Qs[wave * 32 + mt * 16 + ln][ks * 32 + quad * 8];

    // all-ones bf16 B fragment: C[m][n] = sum_k A[m][k] for every lane
    short8 ones_f;
    for (int i = 0; i < 8; i++) ones_f[i] = (short)0x3F80;

    floatx4 acc_o[2][4], acc_l[2];
    for (int mt = 0; mt < 2; mt++) {
        acc_l[mt] = (floatx4)0.0f;
        for (int dt = 0; dt < 4; dt++) acc_o[mt][dt] = (floatx4)0.0f;
    }

    const int mflag = *flag;
    const u16* kb = kk + (((size_t)(b * 2048)) * 16 + h) * 64;
    const u16* vg = vT + (size_t)bh * 131072;

    for (int kv0 = 0; kv0 < 2048; kv0 += 64) {
        __syncthreads();
        for (int c = t; c < 512; c += 256) {
            int row = c >> 3, seg = c & 7;
            *(uint4*)&Ks[row][seg * 8] = *(const uint4*)(kb + (size_t)(kv0 + row) * 1024 + seg * 8);
            *(uint4*)&Vs[row][seg * 8] = *(const uint4*)(vg + (size_t)row * 2048 + kv0 + seg * 8);
        }
        __syncthreads();

        // S = Q K^T  (wave: 32 q rows x 64 kv cols)
        floatx4 acc_s[2][4];
        for (int mt = 0; mt < 2; mt++) for (int nt = 0; nt < 4; nt++) acc_s[mt][nt] = (floatx4)0.0f;
        for (int ks = 0; ks < 2; ks++) {
            for (int nt = 0; nt < 4; nt++) {
                short8 bfr = *(const short8*)&Ks[nt * 16 + ln][ks * 32 + quad * 8];
                acc_s[0][nt] = __builtin_amdgcn_mfma_f32_16x16x32_bf16(qf[0][ks], bfr, acc_s[0][nt], 0, 0, 0);
                acc_s[1][nt] = __builtin_amdgcn_mfma_f32_16x16x32_bf16(qf[1][ks], bfr, acc_s[1][nt], 0, 0, 0);
            }
        }
        if (mflag) {
            for (int mt = 0; mt < 2; mt++)
                for (int nt = 0; nt < 4; nt++)
                    for (int r = 0; r < 4; r++) {
                        int qr = q0 + wave * 32 + mt * 16 + quad * 4 + r;
                        int kc = kv0 + nt * 16 + ln;
                        acc_s[mt][nt][r] += mask[(size_t)qr * 2048 + kc];
                    }
        }

        // P = exp(min(S,60)); no max-subtraction, no shuffles
        for (int mt = 0; mt < 2; mt++) {
            for (int r = 0; r < 4; r++) {
                int prow = wave * 32 + mt * 16 + quad * 4 + r;
                Ps[prow][ln]      = f2b(__expf(fminf(acc_s[mt][0][r], 60.0f)));
                Ps[prow][16 + ln] = f2b(__expf(fminf(acc_s[mt][1][r], 60.0f)));
                Ps[prow][32 + ln] = f2b(__expf(fminf(acc_s[mt][2][r], 60.0f)));
                Ps[prow][48 + ln] = f2b(__expf(fminf(acc_s[mt][3][r], 60.0f)));
            }
        }
        __syncthreads();

        // O += P V ; l += P·1 (ones fragment)
        for (int ks = 0; ks < 2; ks++) {
            short8 a0 = *(const short8*)&Ps[wave * 32 + ln][ks * 32 + quad * 8];
            short8 a1 = *(const short8*)&Ps[wave * 32 + 16 + ln][ks * 32 + quad * 8];
            acc_l[0] = __builtin_amdgcn_mfma_f32_16x16x32_bf16(a0, ones_f, acc_l[0], 0, 0, 0);
            acc_l[1] = __builtin_amdgcn_mfma_f32_16x16x32_bf16(a1, ones_f, acc_l[1], 0, 0, 0);
            for (int dt = 0; dt < 4; dt++) {
                short8 bfr = *(const short8*)&Vs[dt * 16 + ln][ks * 32 + quad * 8];
                acc_o[0][dt] = __builtin_amdgcn_mfma_f32_16x16x32_bf16(a0, bfr, acc_o[0][dt], 0, 0, 0);
                acc_o[1][dt] = __builtin_amdgcn_mfma_f32_16x16x32_bf16(a1, bfr, acc_o[1][dt], 0, 0, 0);
            }
        }
    }

    // write O -> o[b, s, h, d] bf16
    u16* ob = o + (((size_t)(b * 2048 + q0)) * 16 + h) * 64;
    for (int mt = 0; mt < 2; mt++) {
        for (int r = 0; r < 4; r++) {
            float inv = 1.0f / acc_l[mt][r];
            int row = wave * 32 + mt * 16 + quad * 4 + r;
            for (int dt = 0; dt < 4; dt++)
                ob[(size_t)row * 1024 + dt * 16 + ln] = f2b(acc_o[mt][dt][r] * inv);
        }
    }
}

extern "C" void kernel_launch(void* const* d_in, const int* in_sizes, int n_in,
                              void* d_out, int out_size, void* d_ws, size_t ws_size,
                              hipStream_t stream) {
    const float* inp    = (const float*)d_in[0];
    const float* mask   = (const float*)d_in[1];
    const float* rms_s  = (const float*)d_in[2];
    const float* Wq     = (const float*)d_in[3];
    const float* bq     = (const float*)d_in[4];
    const float* Wk     = (const float*)d_in[5];
    const float* bk     = (const float*)d_in[6];
    const float* Wv     = (const float*)d_in[7];
    const float* bv     = (const float*)d_in[8];
    const float* pds    = (const float*)d_in[9];
    const float* Wpost  = (const float*)d_in[10];
    const float* bpost  = (const float*)d_in[11];
    const float* ln_s   = (const float*)d_in[12];
    const float* ln_b   = (const float*)d_in[13];
    const float* W1     = (const float*)d_in[14];
    const float* b1     = (const float*)d_in[15];
    const float* W2     = (const float*)d_in[16];
    const float* b2     = (const float*)d_in[17];
    float* out = (float*)d_out;

    char* w = (char*)d_ws;
    const size_t MB = 1u << 20;
    // [0,8) W1b | [8,16) W2b | [16,32) x -> vT -> h | [32,34)..[38,40) Wq/Wk/Wv/Wp bf16
    // [40,56) qb | [56,72) kb | [72,88) vb -> o | [32,48) yln (after Wq..p+qb dead)
    // [48,112) f1 | flag @112MB
    u16* W1b  = (u16*)(w + 0 * MB);
    u16* W2b  = (u16*)(w + 8 * MB);
    u16* x    = (u16*)(w + 16 * MB);
    u16* vTb  = (u16*)(w + 16 * MB);
    u16* hb   = (u16*)(w + 16 * MB);
    u16* Wqb  = (u16*)(w + 32 * MB);
    u16* Wkb  = (u16*)(w + 34 * MB);
    u16* Wvb  = (u16*)(w + 36 * MB);
    u16* Wpb  = (u16*)(w + 38 * MB);
    u16* qb   = (u16*)(w + 40 * MB);
    u16* kb   = (u16*)(w + 56 * MB);
    u16* vb   = (u16*)(w + 72 * MB);
    u16* o    = vb;                       // over vb (dead after transpose)
    u16* yln  = (u16*)(w + 32 * MB);      // over Wq..p + qb head (dead)
    u16* f1   = (u16*)(w + 48 * MB);      // 64 MB
    int* flag = (int*)(w + 112 * MB);

    // weight pre-convert (fp32 -> bf16), every launch (ws re-poisoned)
    f2b_k<<<1024, 256, 0, stream>>>(Wq, Wqb);
    f2b_k<<<1024, 256, 0, stream>>>(Wk, Wkb);
    f2b_k<<<1024, 256, 0, stream>>>(Wv, Wvb);
    f2b_k<<<1024, 256, 0, stream>>>(Wpost, Wpb);
    f2b_k<<<4096, 256, 0, stream>>>(W1, W1b);
    f2b_k<<<4096, 256, 0, stream>>>(W2, W2b);

    zero_flag_k<<<1, 1, 0, stream>>>(flag);
    mask_any_k<<<4096, 256, 0, stream>>>(mask, flag);

    rmsnorm_k<<<8192, 256, 0, stream>>>(inp, rms_s, x);

    gemm_bt_k<0, false, true><<<dim3(8, 64), 256, 0, stream>>>(x, Wqb, bq, nullptr, qb, 8192, 1024, 1024);
    gemm_bt_k<0, false, true><<<dim3(8, 64), 256, 0, stream>>>(x, Wkb, bk, nullptr, kb, 8192, 1024, 1024);
    gemm_bt_k<0, false, true><<<dim3(8, 64), 256, 0, stream>>>(x, Wvb, bv, nullptr, vb, 8192, 1024, 1024);

    transpose_v_k<<<dim3(32, 64), 256, 0, stream>>>(vb, vTb);   // x dead; vT over x

    attn_k<<<dim3(16, 64), 256, 0, stream>>>(qb, kb, vTb, mask, pds, flag, o);  // o over vb

    gemm_bt_k<2, false, true><<<dim3(8, 64), 256, 0, stream>>>(o, Wpb, bpost, inp, hb, 8192, 1024, 1024);

    layernorm_k<<<8192, 256, 0, stream>>>(hb, ln_s, ln_b, yln);

    gemm_bt_k<1, false, true><<<dim3(32, 64), 256, 0, stream>>>(yln, W1b, b1, nullptr, f1, 8192, 4096, 1024);
    gemm_bt_k<2, true, false><<<dim3(8, 64), 256, 0, stream>>>(f1, W2b, b2, hb, out, 8192, 1024, 4096);
}